// Round 5
// baseline (530.941 us; speedup 1.0000x reference)
//
#include <hip/hip_runtime.h>
#include <stdint.h>

#define B_  32
#define N_  576
#define C_  768
#define H_  12
#define HD_ 64
#define M_  (B_*N_)    // 18432
#define C3_ (3*C_)     // 2304
#define K_  768

typedef __attribute__((ext_vector_type(8))) short short8;
typedef __attribute__((ext_vector_type(4))) float f32x4;

__device__ __forceinline__ uint  f2u(float x){ return __float_as_uint(x); }
__device__ __forceinline__ float u2f(uint x){ return __uint_as_float(x); }

// explicit DMA/LDS drain (attn kernel; merges with compiler waits)
__device__ __forceinline__ void drain_all() {
  asm volatile("s_waitcnt vmcnt(0) lgkmcnt(0)" ::: "memory");
}

// truncation split: hi = top16(a), lo = bf16(a - hi); combined rel err <= 2^-16
__device__ __forceinline__ void split1(float a, ushort& h, ushort& l) {
  uint b0 = f2u(a);
  h = (ushort)(b0 >> 16);
  l = (ushort)(f2u(a - u2f(b0 & 0xffff0000u)) >> 16);
}
__device__ __forceinline__ void split2(float a, float b, uint& hw, uint& lw) {
  uint b0 = f2u(a), b1 = f2u(b);
  uint t0 = b0 & 0xffff0000u, t1 = b1 & 0xffff0000u;
  hw = (b0 >> 16) | t1;
  lw = (f2u(a - u2f(t0)) >> 16) | (f2u(b - u2f(t1)) & 0xffff0000u);
}
// bf16 round-to-nearest-even
__device__ __forceinline__ ushort bf16rn(float x) {
  uint u = f2u(x);
  return (ushort)((u + 0x7fffu + ((u >> 16) & 1u)) >> 16);
}

// async global->LDS 16B DMA; LDS dest is wave-uniform base + lane*16
__device__ __forceinline__ void gload16(const ushort* g, ushort* l) {
  auto gp = (const __attribute__((address_space(1))) uint*)(g);
  auto lp = reinterpret_cast<__attribute__((address_space(3))) uint*>(
              reinterpret_cast<uintptr_t>(l));
  __builtin_amdgcn_global_load_lds(gp, lp, 16, 0, 0);
}

// swizzled 64-wide bf16 tile: logical (row, chunk c of 8 ushorts) at slot
// row*8 + (c ^ (row&7)); DMA writes linear slots carrying the matching chunk.
__device__ __forceinline__ short8 frag_read(const ushort* t, int row, int c) {
  return *(const short8*)&t[((row << 3) + (c ^ (row & 7))) << 3];
}

// elementwise f32 -> (hi,lo) bf16 planes
__global__ __launch_bounds__(256)
void split_f32(const float* __restrict__ src, ushort* __restrict__ hi,
               ushort* __restrict__ lo, int n4) {
  int i = blockIdx.x * 256 + threadIdx.x;
  if (i >= n4) return;
  float4 a = ((const float4*)src)[i];
  uint h0, l0, h1, l1;
  split2(a.x, a.y, h0, l0); split2(a.z, a.w, h1, l1);
  ((uint2*)hi)[i] = make_uint2(h0, h1);
  ((uint2*)lo)[i] = make_uint2(l0, l1);
}

// ---------------------------------------------------------------------------
// Split-bf16 GEMM folded into K' = 3K plain bf16 GEMM (A'=[Ah,Al,Ah],
// B'=[Bh,Bh,Bl] per 64-chunk: sum = hh+lh+hl), run on the m201 8-phase
// 256^2 template: 8 waves (2Mx4N, 128x64/wave), 36 chunks = 18 iters x 2,
// LDS 2dbuf x (A+B) x 256x64 = 128KB, 1 half-tile (2 gloads) staged per
// phase, counted vmcnt(4) at phases 4/8 only, raw s_barrier pairs per
// phase, setprio around each 16-MFMA cluster.
// Stage ledger (race-free): A(2t+1)@ph1,2 -> buf1.A (freed ph8 of t-1);
// B(2t+2)@ph3,4 -> buf0.B (freed ph1); A(2t+2)@ph5,6 -> buf0.A (freed ph4);
// B(2t+3)@ph7,8 -> buf1.B (freed ph5). vmcnt(4)@ph8 guards chunk 2t+2,
// vmcnt(4)@ph4 guards chunk 2t+1 (exactly 2 halves issued after the
// guarded chunk's last half). t=17 ph4 uses vmcnt(0) (stages skipped).
// EPI 0: scatter q/k (split, q pre-scaled 0.125) + v (bf16, transposed)
// EPI 1: f32 output + bias (proj)
// ---------------------------------------------------------------------------
#define BAR_IN  { __builtin_amdgcn_sched_barrier(0); __builtin_amdgcn_s_barrier(); \
                  asm volatile("s_waitcnt lgkmcnt(0)" ::: "memory"); \
                  __builtin_amdgcn_sched_barrier(0); }
#define BAR_OUT { __builtin_amdgcn_sched_barrier(0); __builtin_amdgcn_s_barrier(); }
#define RD_B(Bb) { _Pragma("unroll") for (int j = 0; j < 4; j++) { \
    b[j][0] = *(const short8*)&(Bb)[bslot[j] << 3]; \
    b[j][1] = *(const short8*)&(Bb)[(bslot[j] ^ 4) << 3]; } }
#define RD_A(Ab, i0) { _Pragma("unroll") for (int ii = 0; ii < 2; ii++) { \
    a[ii][0] = *(const short8*)&(Ab)[aslot[(i0) + ii] << 3]; \
    a[ii][1] = *(const short8*)&(Ab)[(aslot[(i0) + ii] ^ 4) << 3]; } }
#define DO_MFMA(i0) { __builtin_amdgcn_s_setprio(1); \
    _Pragma("unroll") for (int j = 0; j < 4; j++) \
    _Pragma("unroll") for (int ii = 0; ii < 2; ii++) \
    _Pragma("unroll") for (int kk = 0; kk < 2; kk++) \
      acc[(i0) + ii][j] = __builtin_amdgcn_mfma_f32_16x16x32_bf16( \
          a[ii][kk], b[j][kk], acc[(i0) + ii][j], 0, 0, 0); \
    __builtin_amdgcn_s_setprio(0); }

template<int EPI>
__global__ __launch_bounds__(512, 2)
void gemm_mfma(const ushort* __restrict__ Ah, const ushort* __restrict__ Al,
               const ushort* __restrict__ Bh, const ushort* __restrict__ Bl,
               const float* __restrict__ bias, float* __restrict__ Cf,
               ushort* __restrict__ QpH, ushort* __restrict__ QpL,
               ushort* __restrict__ KpH, ushort* __restrict__ KpL,
               ushort* __restrict__ Vt, int Nout) {
  // [buf][part: A,B][256 rows x 8 chunk-slots x 8 ushorts]
  __shared__ ushort S[2][2][16384];

  const int tid  = threadIdx.x;
  const int lane = tid & 63, wave = tid >> 6;
  const int ln15 = lane & 15, cq = lane >> 4;
  const int wrow = (wave >> 2) << 7, wcol = (wave & 3) << 6;

  // XCD-aware bijective swizzle: both grids (648, 216 wgs) are %8 == 0
  const int nbx  = gridDim.x;
  const int nwg  = nbx * gridDim.y;
  const int orig = blockIdx.y * nbx + blockIdx.x;
  const int swz  = (orig & 7) * (nwg >> 3) + (orig >> 3);
  const int m0 = (swz / nbx) << 8, n0 = (swz % nbx) << 8;

  int aslot[8], bslot[4];
#pragma unroll
  for (int i = 0; i < 8; i++) {
    const int r = wrow + (i << 4) + ln15;
    aslot[i] = (r << 3) + (cq ^ (r & 7));
  }
#pragma unroll
  for (int j = 0; j < 4; j++) {
    const int r = wcol + (j << 4) + ln15;
    bslot[j] = (r << 3) + (cq ^ (r & 7));
  }

  // per-thread staging geometry: 2 gloads per half-tile (128 rows x 64)
  int srow[2], sc8[2], soff[2];
#pragma unroll
  for (int pi = 0; pi < 2; pi++) {
    const int u = (((wave << 1) + pi) << 6) + lane;
    srow[pi] = u >> 3;
    sc8[pi]  = (u & 7) ^ (srow[pi] & 7);
    soff[pi] = u << 3;
  }

  // stage half h (0=A0,1=A1,2=B0,3=B1) of K'-chunk c; dest buf = c&1
  auto stage = [&](int c, int h) {
    const int q = c / 3, p = c - 3 * q;
    const ushort* src = (h < 2) ? ((p == 1) ? Al : Ah)
                                : ((p == 2) ? Bl : Bh);
    const int rb = ((h < 2) ? m0 : n0) + ((h & 1) << 7);
    ushort* dst = &S[c & 1][h >> 1][(h & 1) << 13];
    const int kb = q << 6;
#pragma unroll
    for (int pi = 0; pi < 2; pi++)
      gload16(src + (size_t)(rb + srow[pi]) * K_ + kb + (sc8[pi] << 3),
              dst + soff[pi]);
  };

  f32x4 acc[8][4];
#pragma unroll
  for (int i = 0; i < 8; i++)
#pragma unroll
    for (int j = 0; j < 4; j++) acc[i][j] = (f32x4)0.f;

  // prologue: chunk0 (A0,A1,B0,B1) then chunk1 (B first, A last)
  stage(0, 0); stage(0, 1); stage(0, 2); stage(0, 3);
  stage(1, 2); stage(1, 3); stage(1, 0); stage(1, 1);
  asm volatile("s_waitcnt vmcnt(8)" ::: "memory");   // chunk0 landed
  __builtin_amdgcn_s_barrier();
  __builtin_amdgcn_sched_barrier(0);

  const ushort* A0b = &S[0][0][0];
  const ushort* B0b = &S[0][1][0];
  const ushort* A1b = &S[1][0][0];
  const ushort* B1b = &S[1][1][0];

  constexpr int NIT = (3 * K_) / 128;   // 18 iterations, 2 chunks each
#pragma unroll 1
  for (int t = 0; t < NIT; ++t) {
    const int c1 = 2 * t + 1, c2 = 2 * t + 2, c3 = 2 * t + 3;
    short8 b[4][2], a[2][2];

    // ---- phase 1: chunk 2t (buf0), i 0-1; stage A0(2t+1) ----
    if (t > 0) stage(c1, 0);
    RD_B(B0b); RD_A(A0b, 0);
    BAR_IN; DO_MFMA(0); BAR_OUT;
    // ---- phase 2: i 2-3; stage A1(2t+1) ----
    if (t > 0) stage(c1, 1);
    RD_A(A0b, 2);
    BAR_IN; DO_MFMA(2); BAR_OUT;
    // ---- phase 3: i 4-5; stage B0(2t+2) (buf0.B freed at ph1) ----
    if (c2 < 36) stage(c2, 2);
    RD_A(A0b, 4);
    BAR_IN; DO_MFMA(4); BAR_OUT;
    // ---- phase 4: i 6-7; stage B1(2t+2); vmcnt guards chunk 2t+1 ----
    if (c2 < 36) stage(c2, 3);
    RD_A(A0b, 6);
    BAR_IN; DO_MFMA(6);
    if (t < NIT - 1) asm volatile("s_waitcnt vmcnt(4)" ::: "memory");
    else             asm volatile("s_waitcnt vmcnt(0)" ::: "memory");
    BAR_OUT;
    // ---- phase 5: chunk 2t+1 (buf1), i 0-1; stage A0(2t+2) ----
    if (c2 < 36) stage(c2, 0);
    RD_B(B1b); RD_A(A1b, 0);
    BAR_IN; DO_MFMA(0); BAR_OUT;
    // ---- phase 6: i 2-3; stage A1(2t+2) ----
    if (c2 < 36) stage(c2, 1);
    RD_A(A1b, 2);
    BAR_IN; DO_MFMA(2); BAR_OUT;
    // ---- phase 7: i 4-5; stage B0(2t+3) (buf1.B freed at ph5) ----
    if (c3 < 36) stage(c3, 2);
    RD_A(A1b, 4);
    BAR_IN; DO_MFMA(4); BAR_OUT;
    // ---- phase 8: i 6-7; stage B1(2t+3); vmcnt guards chunk 2t+2 ----
    if (c3 < 36) stage(c3, 3);
    RD_A(A1b, 6);
    BAR_IN; DO_MFMA(6);
    if (t < NIT - 1) {
      asm volatile("s_waitcnt vmcnt(4)" ::: "memory");
      BAR_OUT;
    }
  }

  // epilogue: C/D layout col=lane&15, row=(lane>>4)*4+reg
  if (EPI == 1) {
#pragma unroll
    for (int j = 0; j < 4; j++) {
      const int col = n0 + wcol + (j << 4) + ln15;
      const float bv = bias[col];
#pragma unroll
      for (int i = 0; i < 8; i++)
#pragma unroll
        for (int r = 0; r < 4; r++) {
          const int row_g = m0 + wrow + (i << 4) + (cq << 2) + r;
          Cf[(size_t)row_g * Nout + col] = acc[i][j][r] + bv;
        }
    }
  } else {
#pragma unroll
    for (int j = 0; j < 4; j++) {
      const int col = n0 + wcol + (j << 4) + ln15;
      const int which = col / 768;              // block-uniform (768 = 3*256)
      const int hh = (col % 768) >> 6;
      const int dd = col & 63;
      const float bv = bias[col];
      const float scale = (which == 0) ? 0.125f : 1.f;
#pragma unroll
      for (int i = 0; i < 8; i++) {
        const int base_row = m0 + wrow + (i << 4) + (cq << 2);
        const int b = base_row / 576;           // constant across r (4 | 576)
        const int n = base_row - b * 576;
        const size_t bh = (size_t)b * H_ + hh;
        if (which == 2) {                       // V -> single bf16, (b,h,d,n)
          ushort hv[4];
#pragma unroll
          for (int r = 0; r < 4; r++) hv[r] = bf16rn(acc[i][j][r] + bv);
          const size_t dst = (bh * 64 + dd) * 576 + n;
          *(ushort4*)&Vt[dst] = make_ushort4(hv[0], hv[1], hv[2], hv[3]);
        } else {                                // Q/K -> split planes (b,h,n,d)
          ushort* dh = which ? KpH : QpH;
          ushort* dl = which ? KpL : QpL;
#pragma unroll
          for (int r = 0; r < 4; r++) {
            ushort hs, ls;
            split1((acc[i][j][r] + bv) * scale, hs, ls);
            const size_t dst = (bh * 576 + n + r) * 64 + dd;
            dh[dst] = hs; dl[dst] = ls;
          }
        }
      }
    }
  }
}

// ---------------------------------------------------------------------------
// MFMA flash attention, block-causal. Q/K split (3-product S), V+P plain bf16
// (1-product PV). P stays wave-private -> lgkm wait only. K/V staging
// double-buffered with counted vmcnt(6) + raw s_barrier. LDS 72KB.
// ---------------------------------------------------------------------------
__global__ __launch_bounds__(256)
void attn_mfma(const ushort* __restrict__ QH, const ushort* __restrict__ QL,
               const ushort* __restrict__ KHp, const ushort* __restrict__ KLp,
               const ushort* __restrict__ Vp,
               ushort* __restrict__ OH, ushort* __restrict__ OL) {
  __shared__ ushort qh_s[64*64], ql_s[64*64];
  __shared__ ushort kh_s[2][64*64], kl_s[2][64*64];
  __shared__ ushort vh_s[2][64*64];
  __shared__ ushort p_s[64*64];

  const int tid  = threadIdx.x;
  const int lane = tid & 63, wave = tid >> 6;
  const int ln15 = lane & 15, quad = lane >> 4;
  const int qt = blockIdx.x;                  // 0..8
  const int bh = blockIdx.y;                  // 0..383
  const int q0 = qt << 6;
  const size_t pbase = (size_t)bh * (576 * 64);

  // per-wave staging geometry: 2 parts x (16B per lane)
  int sbs[2], srow[2], scol[2];
#pragma unroll
  for (int p = 0; p < 2; p++) {
    const int bs = ((wave << 1) + p) << 6;
    const int s = bs + lane, row = s >> 3, c = (s & 7) ^ (row & 7);
    sbs[p] = bs << 3; srow[p] = row; scol[p] = c << 3;
  }

  // stage Q (hi/lo): 4 DMAs per wave
#pragma unroll
  for (int p = 0; p < 2; p++) {
    const size_t off = pbase + (size_t)(q0 + srow[p]) * 64 + scol[p];
    gload16(QH + off, &qh_s[sbs[p]]);
    gload16(QL + off, &ql_s[sbs[p]]);
  }

  int bi_q[4];
#pragma unroll
  for (int r = 0; r < 4; r++) {
    const int p = q0 + (wave << 4) + (quad << 2) + r;
    bi_q[r] = (p / 96) * 6 + ((p % 24) >> 2);
  }
  const int qmax = 6 * ((qt * 64 + 159) / 96) - 1;
  const int qmin = 6 * ((2 * qt) / 3);

  // active K-tiles form a prefix (tmink nondecreasing in kt)
  int nkt = 0;
#pragma unroll
  for (int kt = 0; kt < 9; ++kt)
    if (6 * ((2 * kt) / 3) <= qmax) nkt = kt + 1;

  // prologue: stage K/V tile 0 into buf 0 (6 DMAs per wave)
#pragma unroll
  for (int p = 0; p < 2; p++) {
    const size_t koff = pbase + (size_t)srow[p] * 64 + scol[p];
    gload16(KHp + koff, &kh_s[0][sbs[p]]);
    gload16(KLp + koff, &kl_s[0][sbs[p]]);
    const size_t voff = pbase + (size_t)srow[p] * 576 + scol[p];
    gload16(Vp + voff, &vh_s[0][sbs[p]]);
  }

  f32x4 oacc[4];
#pragma unroll
  for (int dt = 0; dt < 4; dt++) oacc[dt] = (f32x4)0.f;
  float mrun[4], lrun[4];
#pragma unroll
  for (int r = 0; r < 4; r++) { mrun[r] = -1e30f; lrun[r] = 0.f; }

  int cur = 0;
  for (int kt = 0; kt < nkt; ++kt) {
    const int tmaxk = 6 * ((kt * 64 + 159) / 96) - 1;
    const bool nomask = (tmaxk <= qmin);

    // prefetch tile kt+1 into the other buffer; wait for tile kt with my
    // 6 newest (kt+1) still in flight -> counted, never 0 mid-loop.
    if (kt + 1 < nkt) {
      const int nx = cur ^ 1;
#pragma unroll
      for (int p = 0; p < 2; p++) {
        const size_t koff = pbase + (size_t)(((kt + 1) << 6) + srow[p]) * 64 + scol[p];
        gload16(KHp + koff, &kh_s[nx][sbs[p]]);
        gload16(KLp + koff, &kl_s[nx][sbs[p]]);
        const size_t voff = pbase + (size_t)srow[p] * 576 + ((kt + 1) << 6) + scol[p];
        gload16(Vp + voff, &vh_s[nx][sbs[p]]);
      }
      asm volatile("s_waitcnt vmcnt(6)" ::: "memory");
    } else {
      asm volatile("s_waitcnt vmcnt(0)" ::: "memory");
    }
    __builtin_amdgcn_sched_barrier(0);
    __builtin_amdgcn_s_barrier();

    // S = Q K^T  (pre-scaled by 0.125 via Q)
    const ushort* khc = &kh_s[cur][0];
    const ushort* klc = &kl_s[cur][0];
    const ushort* vhc = &vh_s[cur][0];
    f32x4 sacc[4];
#pragma unroll
    for (int j = 0; j < 4; j++) sacc[j] = (f32x4)0.f;
#pragma unroll
    for (int s2 = 0; s2 < 2; ++s2) {
      const short8 aqh = frag_read(qh_s, (wave << 4) + ln15, (s2 << 2) + quad);
      const short8 aql = frag_read(ql_s, (wave << 4) + ln15, (s2 << 2) + quad);
#pragma unroll
      for (int j = 0; j < 4; j++) {
        const short8 bkh = frag_read(khc, (j << 4) + ln15, (s2 << 2) + quad);
        const short8 bkl = frag_read(klc, (j << 4) + ln15, (s2 << 2) + quad);
        sacc[j] = __builtin_amdgcn_mfma_f32_16x16x32_bf16(aqh, bkh, sacc[j], 0, 0, 0);
        sacc[j] = __builtin_amdgcn_mfma_f32_16x16x32_bf16(aqh, bkl, sacc[j], 0, 0, 0);
        sacc[j] = __builtin_amdgcn_mfma_f32_16x16x32_bf16(aql, bkh, sacc[j], 0, 0, 0);
      }
    }

    float sv[4][4];
#pragma unroll
    for (int j = 0; j < 4; j++)
#pragma unroll
      for (int r = 0; r < 4; r++) sv[j][r] = sacc[j][r];

    if (!nomask) {
      int bi_k[4];
#pragma unroll
      for (int j = 0; j < 4; j++) {
        const int p = (kt << 6) + (j << 4) + ln15;
        bi_k[j] = (p / 96) * 6 + ((p % 24) >> 2);
      }
#pragma unroll
      for (int j = 0; j < 4; j++)
#pragma unroll
        for (int r = 0; r < 4; r++)
          if (bi_k[j] > bi_q[r]) sv[j][r] = -1e30f;
    }

    // online softmax; row r lives in the 16 lanes of this quad
#pragma unroll
    for (int r = 0; r < 4; r++) {
      float rm = fmaxf(fmaxf(sv[0][r], sv[1][r]), fmaxf(sv[2][r], sv[3][r]));
      rm = fmaxf(rm, __shfl_xor(rm, 1));
      rm = fmaxf(rm, __shfl_xor(rm, 2));
      rm = fmaxf(rm, __shfl_xor(rm, 4));
      rm = fmaxf(rm, __shfl_xor(rm, 8));
      const float mnew  = fmaxf(mrun[r], rm);
      const float alpha = __expf(mrun[r] - mnew);
      float rs = 0.f;
#pragma unroll
      for (int j = 0; j < 4; j++) {
        const float pj = __expf(sv[j][r] - mnew);
        sv[j][r] = pj; rs += pj;
      }
      rs += __shfl_xor(rs, 1);
      rs += __shfl_xor(rs, 2);
      rs += __shfl_xor(rs, 4);
      rs += __shfl_xor(rs, 8);
      lrun[r] = lrun[r] * alpha + rs;
      mrun[r] = mnew;
#pragma unroll
      for (int dt = 0; dt < 4; dt++) oacc[dt][r] *= alpha;
    }

    // P (bf16) -> own rows of p_s; wave-private, only a lgkm wait needed
#pragma unroll
    for (int j = 0; j < 4; j++)
#pragma unroll
      for (int r = 0; r < 4; r++) {
        const int row = (wave << 4) + (quad << 2) + r;
        const int col = (j << 4) + ln15;
        const int c = col >> 3, e = col & 7;
        p_s[(((row << 3) + (c ^ (row & 7))) << 3) + e] = bf16rn(sv[j][r]);
      }
    asm volatile("s_waitcnt lgkmcnt(0)" ::: "memory");

    // O += P V
#pragma unroll
    for (int s2 = 0; s2 < 2; ++s2) {
      const short8 pf = frag_read(p_s, (wave << 4) + ln15, (s2 << 2) + quad);
#pragma unroll
      for (int dt = 0; dt < 4; dt++) {
        const short8 bvh = frag_read(vhc, (dt << 4) + ln15, (s2 << 2) + quad);
        oacc[dt] = __builtin_amdgcn_mfma_f32_16x16x32_bf16(pf, bvh, oacc[dt], 0, 0, 0);
      }
    }

    __builtin_amdgcn_sched_barrier(0);
    __builtin_amdgcn_s_barrier();
    cur ^= 1;
  }

  // normalize + write split planes, token-major (M, C) for the proj GEMM
  const int b = bh / H_, h = bh % H_;
#pragma unroll
  for (int r = 0; r < 4; r++) {
    const float inv = 1.f / lrun[r];
    const int row_g = b * 576 + q0 + (wave << 4) + (quad << 2) + r;
#pragma unroll
    for (int dt = 0; dt < 4; dt++) {
      const float v = oacc[dt][r] * inv;
      ushort hs, ls;
      split1(v, hs, ls);
      const size_t dst = (size_t)row_g * 768 + h * 64 + (dt << 4) + ln15;
      OH[dst] = hs; OL[dst] = ls;
    }
  }
}

// ---------------------------------------------------------------------------
extern "C" void kernel_launch(void* const* d_in, const int* in_sizes, int n_in,
                              void* d_out, int out_size, void* d_ws, size_t ws_size,
                              hipStream_t stream) {
  const float* x      = (const float*)d_in[0];
  const float* qkv_w  = (const float*)d_in[1];
  const float* qkv_b  = (const float*)d_in[2];
  const float* proj_w = (const float*)d_in[3];
  const float* proj_b = (const float*)d_in[4];
  float* out = (float*)d_out;

  // ws layout (peak 205 MB < proven 226.5 MB):
  // [Qp hi/lo][Kp hi/lo][Vt] planes 0-4; [XH][XL] planes 5-6 (x split, dead
  // after QKV -> overlaid by attn-out AH/AL); [QW hi/lo 7.1MB at 7nP, dead
  // after QKV -> overlaid by PW hi/lo (split AFTER attention, round-3 order)].
  ushort* ws = (ushort*)d_ws;
  const size_t nP = (size_t)B_ * H_ * 576 * 64;   // 14,155,776 (= M_*C_)
  ushort* QpH = ws + 0 * nP;
  ushort* QpL = ws + 1 * nP;
  ushort* KpH = ws + 2 * nP;
  ushort* KpL = ws + 3 * nP;
  ushort* Vt  = ws + 4 * nP;
  ushort* XH  = ws + 5 * nP;                      // x split planes
  ushort* XL  = ws + 6 * nP;
  ushort* AH  = ws + 5 * nP;                      // attn out (overlay X planes)
  ushort* AL  = ws + 6 * nP;
  ushort* QWH = ws + 7 * nP;                      // qkv_w split
  ushort* QWL = QWH + (size_t)C3_ * C_;
  ushort* PWH = ws + 7 * nP;                      // proj_w split (overlay QW)
  ushort* PWL = PWH + (size_t)C_ * C_;

  // 1) split x and qkv_w
  split_f32<<<(M_*K_/4 + 255)/256, 256, 0, stream>>>(x, XH, XL, M_*K_/4);
  split_f32<<<(C3_*C_/4 + 255)/256, 256, 0, stream>>>(qkv_w, QWH, QWL, C3_*C_/4);

  // 2) qkv GEMM (8-phase K'-folded), epilogue scatters q/k/v planes
  gemm_mfma<0><<<dim3(C3_/256, M_/256), 512, 0, stream>>>(
      XH, XL, QWH, QWL, qkv_b, nullptr, QpH, QpL, KpH, KpL, Vt, C3_);

  // 3) attention (X planes now dead; writes AH/AL over them)
  attn_mfma<<<dim3(9, B_*H_), 256, 0, stream>>>(
      QpH, QpL, KpH, KpL, Vt, AH, AL);

  // 4) split proj_w (QW region dead after QKV GEMM)
  split_f32<<<(C_*C_/4 + 255)/256, 256, 0, stream>>>(proj_w, PWH, PWL, C_*C_/4);

  // 5) proj GEMM -> f32 out
  gemm_mfma<1><<<dim3(C_/256, M_/256), 512, 0, stream>>>(
      AH, AL, PWH, PWL, proj_b, out,
      nullptr, nullptr, nullptr, nullptr, nullptr, C_);
}

// Round 6
// 332.211 us; speedup vs baseline: 1.5982x; 1.5982x over previous
//
#include <hip/hip_runtime.h>
#include <stdint.h>

#define B_  32
#define N_  576
#define C_  768
#define H_  12
#define HD_ 64
#define M_  (B_*N_)    // 18432
#define C3_ (3*C_)     // 2304
#define K_  768

typedef __attribute__((ext_vector_type(8))) _Float16 half8;
typedef __attribute__((ext_vector_type(4))) float f32x4;

// f32 -> f16 round-to-nearest-even
__device__ __forceinline__ ushort f16rn(float x) {
  return __builtin_bit_cast(unsigned short, (_Float16)x);
}

// async global->LDS 16B DMA; LDS dest is wave-uniform base + lane*16
__device__ __forceinline__ void gload16(const ushort* g, ushort* l) {
  auto gp = (const __attribute__((address_space(1))) uint*)(g);
  auto lp = reinterpret_cast<__attribute__((address_space(3))) uint*>(
              reinterpret_cast<uintptr_t>(l));
  __builtin_amdgcn_global_load_lds(gp, lp, 16, 0, 0);
}

// swizzled 64-wide f16 tile: logical (row, chunk c of 8 halves) at slot
// row*8 + (c ^ (row&7)); DMA writes linear slots carrying the matching chunk.
__device__ __forceinline__ half8 frag_read(const ushort* t, int row, int c) {
  return *(const half8*)&t[((row << 3) + (c ^ (row & 7))) << 3];
}

// elementwise f32 -> f16 plane
__global__ __launch_bounds__(256)
void cvt_f16(const float* __restrict__ src, ushort* __restrict__ dst, int n4) {
  int i = blockIdx.x * 256 + threadIdx.x;
  if (i >= n4) return;
  float4 a = ((const float4*)src)[i];
  ((ushort4*)dst)[i] = make_ushort4(f16rn(a.x), f16rn(a.y), f16rn(a.z), f16rn(a.w));
}

// ---------------------------------------------------------------------------
// Plain f16 single-product MFMA GEMM (replaces the split-bf16 3-product:
// 3x fewer MFMA, half the planes). 256x256 tile, BK=32, 8 waves (2Mx4N,
// 128x64/wave), double-buffered LDS 64KB -> 2 blocks/CU (4 waves/SIMD:
// cross-block overlap the 1-block/CU split variants never had), counted
// vmcnt(4) (never 0 mid-loop), raw s_barrier, setprio'd MFMA cluster,
// bijective XCD swizzle.
// EPI 0: scatter q (f16, pre-scaled 0.125) / k (f16) / v (f16, transposed)
// EPI 1: f32 output + bias (proj)
// ---------------------------------------------------------------------------
template<int EPI>
__global__ __launch_bounds__(512, 2)
void gemm_mfma(const ushort* __restrict__ A, const ushort* __restrict__ Bm,
               const float* __restrict__ bias, float* __restrict__ Cf,
               ushort* __restrict__ Qp, ushort* __restrict__ Kp,
               ushort* __restrict__ Vt, int Nout) {
  // [dbuf][plane: A,B][256 rows x 4 chunk-slots x 8 halves]
  __shared__ ushort S[2][2][8192];

  const int tid  = threadIdx.x;
  const int lane = tid & 63, wave = tid >> 6;
  const int ln15 = lane & 15, cq = lane >> 4;
  const int wrow = (wave >> 2) << 7, wcol = (wave & 3) << 6;

  // XCD-aware bijective swizzle: both grids (648, 216 wgs) are %8 == 0
  const int nbx  = gridDim.x;
  const int nwg  = nbx * gridDim.y;
  const int orig = blockIdx.y * nbx + blockIdx.x;
  const int swz  = (orig & 7) * (nwg >> 3) + (orig >> 3);
  const int m0 = (swz / nbx) << 8, n0 = (swz % nbx) << 8;

  int aslot[8], bslot[4];
#pragma unroll
  for (int i = 0; i < 8; i++) {
    const int r = wrow + (i << 4) + ln15;
    aslot[i] = (r << 2) + (cq ^ ((r >> 1) & 3));
  }
#pragma unroll
  for (int j = 0; j < 4; j++) {
    const int r = wcol + (j << 4) + ln15;
    bslot[j] = (r << 2) + (cq ^ ((r >> 1) & 3));
  }

  // staging: per wave 2 parts x (A + B) 1KB DMAs = 4 per K-step
  int ldso[2];
  const ushort *pA[2], *pB[2];
#pragma unroll
  for (int p = 0; p < 2; p++) {
    const int bs = ((wave << 1) + p) << 6;
    const int s = bs + lane, row = s >> 2, c = (s & 3) ^ ((row >> 1) & 3);
    ldso[p] = bs << 3;
    pA[p] = A  + (size_t)(m0 + row) * K_ + (c << 3);
    pB[p] = Bm + (size_t)(n0 + row) * K_ + (c << 3);
  }

  auto issue4 = [&](int d, int k0) {
#pragma unroll
    for (int p = 0; p < 2; p++) {
      gload16(pA[p] + k0, &S[d][0][ldso[p]]);
      gload16(pB[p] + k0, &S[d][1][ldso[p]]);
    }
  };

  f32x4 acc[8][4];
#pragma unroll
  for (int i = 0; i < 8; i++)
#pragma unroll
    for (int j = 0; j < 4; j++) acc[i][j] = (f32x4)0.f;

  // prologue: tiles 0 and 1 in flight; wait tile 0 (my 4 newest stay out)
  issue4(0, 0);
  issue4(1, 32);
  asm volatile("s_waitcnt vmcnt(4)" ::: "memory");
  __builtin_amdgcn_s_barrier();
  __builtin_amdgcn_sched_barrier(0);

  constexpr int NT = K_ / 32;   // 24
  for (int t = 0; t < NT; ++t) {
    const int cur = t & 1;
    const ushort* As = &S[cur][0][0];
    const ushort* Bs = &S[cur][1][0];

    half8 bfr[4], afr[8];
#pragma unroll
    for (int j = 0; j < 4; j++) bfr[j] = *(const half8*)&Bs[bslot[j] << 3];
#pragma unroll
    for (int i = 0; i < 8; i++) afr[i] = *(const half8*)&As[aslot[i] << 3];

    __builtin_amdgcn_s_setprio(1);
#pragma unroll
    for (int j = 0; j < 4; ++j)
#pragma unroll
      for (int i = 0; i < 8; ++i)
        acc[i][j] = __builtin_amdgcn_mfma_f32_16x16x32_f16(afr[i], bfr[j], acc[i][j], 0, 0, 0);
    __builtin_amdgcn_s_setprio(0);

    if (t == NT - 1) break;
    // reads of S[cur] done -> barrier -> prefetch t+2 into S[cur] ->
    // wait tile t+1 landed (4 newest stay in flight) -> barrier
    asm volatile("s_waitcnt lgkmcnt(0)" ::: "memory");
    __builtin_amdgcn_sched_barrier(0);
    __builtin_amdgcn_s_barrier();
    if (t + 2 < NT) {
      issue4(cur, (t + 2) << 5);
      asm volatile("s_waitcnt vmcnt(4)" ::: "memory");
    } else {
      asm volatile("s_waitcnt vmcnt(0)" ::: "memory");
    }
    __builtin_amdgcn_s_barrier();
    __builtin_amdgcn_sched_barrier(0);
  }

  // epilogue: C/D layout col=lane&15, row=(lane>>4)*4+reg
  if (EPI == 1) {
#pragma unroll
    for (int j = 0; j < 4; j++) {
      const int col = n0 + wcol + (j << 4) + ln15;
      const float bv = bias[col];
#pragma unroll
      for (int i = 0; i < 8; i++)
#pragma unroll
        for (int r = 0; r < 4; r++) {
          const int row_g = m0 + wrow + (i << 4) + (cq << 2) + r;
          Cf[(size_t)row_g * Nout + col] = acc[i][j][r] + bv;
        }
    }
  } else {
#pragma unroll
    for (int j = 0; j < 4; j++) {
      const int col = n0 + wcol + (j << 4) + ln15;
      const int which = col / 768;              // block-uniform (768 = 3*256)
      const int hh = (col % 768) >> 6;
      const int dd = col & 63;
      const float bv = bias[col];
      const float scale = (which == 0) ? 0.125f : 1.f;
#pragma unroll
      for (int i = 0; i < 8; i++) {
        const int base_row = m0 + wrow + (i << 4) + (cq << 2);
        const int b = base_row / 576;           // constant across r (4 | 576)
        const int n = base_row - b * 576;
        const size_t bh = (size_t)b * H_ + hh;
        if (which == 2) {                       // V -> f16, (b,h,d,n)
          ushort hv[4];
#pragma unroll
          for (int r = 0; r < 4; r++) hv[r] = f16rn(acc[i][j][r] + bv);
          const size_t dst = (bh * 64 + dd) * 576 + n;
          *(ushort4*)&Vt[dst] = make_ushort4(hv[0], hv[1], hv[2], hv[3]);
        } else {                                // Q/K -> f16 plane (b,h,n,d)
          ushort* d = which ? Kp : Qp;
#pragma unroll
          for (int r = 0; r < 4; r++)
            d[(bh * 576 + n + r) * 64 + dd] = f16rn((acc[i][j][r] + bv) * scale);
        }
      }
    }
  }
}

// ---------------------------------------------------------------------------
// MFMA flash attention, block-causal, all-f16 single-product (8 MFMA QK^T +
// 8 MFMA PV per tile vs 24+8 in the split version). K/V double-buffered with
// counted vmcnt(4) + raw s_barrier. LDS 48KB -> 3 blocks/CU.
// ---------------------------------------------------------------------------
__global__ __launch_bounds__(256, 3)
void attn_mfma(const ushort* __restrict__ Qp, const ushort* __restrict__ Kp,
               const ushort* __restrict__ Vp, ushort* __restrict__ Ap) {
  __shared__ ushort qs[4096], ks[2][4096], vs[2][4096], ps[4096];

  const int tid  = threadIdx.x;
  const int lane = tid & 63, wave = tid >> 6;
  const int ln15 = lane & 15, quad = lane >> 4;
  const int qt = blockIdx.x;                  // 0..8
  const int bh = blockIdx.y;                  // 0..383
  const int q0 = qt << 6;
  const size_t pbase = (size_t)bh * (576 * 64);

  // per-wave staging geometry: 2 parts x (16B per lane) covers 64x64 f16
  int sbs[2], srow[2], scol[2];
#pragma unroll
  for (int p = 0; p < 2; p++) {
    const int bs = ((wave << 1) + p) << 6;
    const int s = bs + lane, row = s >> 3, c = (s & 7) ^ (row & 7);
    sbs[p] = bs << 3; srow[p] = row; scol[p] = c << 3;
  }

  // stage Q (2 DMAs per wave)
#pragma unroll
  for (int p = 0; p < 2; p++)
    gload16(Qp + pbase + (size_t)(q0 + srow[p]) * 64 + scol[p], &qs[sbs[p]]);

  int bi_q[4];
#pragma unroll
  for (int r = 0; r < 4; r++) {
    const int p = q0 + (wave << 4) + (quad << 2) + r;
    bi_q[r] = (p / 96) * 6 + ((p % 24) >> 2);
  }
  const int qmax = 6 * ((qt * 64 + 159) / 96) - 1;
  const int qmin = 6 * ((2 * qt) / 3);

  // active K-tiles form a prefix (tmink nondecreasing in kt)
  int nkt = 0;
#pragma unroll
  for (int kt = 0; kt < 9; ++kt)
    if (6 * ((2 * kt) / 3) <= qmax) nkt = kt + 1;

  // prologue: stage K/V tile 0 into buf 0 (4 DMAs per wave)
#pragma unroll
  for (int p = 0; p < 2; p++) {
    gload16(Kp + pbase + (size_t)srow[p] * 64 + scol[p], &ks[0][sbs[p]]);
    gload16(Vp + pbase + (size_t)srow[p] * 576 + scol[p], &vs[0][sbs[p]]);
  }

  f32x4 oacc[4];
#pragma unroll
  for (int dt = 0; dt < 4; dt++) oacc[dt] = (f32x4)0.f;
  float mrun[4], lrun[4];
#pragma unroll
  for (int r = 0; r < 4; r++) { mrun[r] = -1e30f; lrun[r] = 0.f; }

  int cur = 0;
  for (int kt = 0; kt < nkt; ++kt) {
    const int tmaxk = 6 * ((kt * 64 + 159) / 96) - 1;
    const bool nomask = (tmaxk <= qmin);

    // prefetch tile kt+1 into the other buffer; wait tile kt with my 4
    // newest (kt+1) still in flight -> counted, never 0 mid-loop.
    if (kt + 1 < nkt) {
      const int nx = cur ^ 1;
#pragma unroll
      for (int p = 0; p < 2; p++) {
        gload16(Kp + pbase + (size_t)(((kt + 1) << 6) + srow[p]) * 64 + scol[p],
                &ks[nx][sbs[p]]);
        gload16(Vp + pbase + (size_t)srow[p] * 576 + ((kt + 1) << 6) + scol[p],
                &vs[nx][sbs[p]]);
      }
      asm volatile("s_waitcnt vmcnt(4)" ::: "memory");
    } else {
      asm volatile("s_waitcnt vmcnt(0)" ::: "memory");
    }
    __builtin_amdgcn_sched_barrier(0);
    __builtin_amdgcn_s_barrier();

    // S = Q K^T  (pre-scaled by 0.125 via Q)
    const ushort* khc = &ks[cur][0];
    const ushort* vhc = &vs[cur][0];
    f32x4 sacc[4];
#pragma unroll
    for (int j = 0; j < 4; j++) sacc[j] = (f32x4)0.f;
#pragma unroll
    for (int s2 = 0; s2 < 2; ++s2) {
      const half8 aq = frag_read(qs, (wave << 4) + ln15, (s2 << 2) + quad);
#pragma unroll
      for (int j = 0; j < 4; j++) {
        const half8 bk = frag_read(khc, (j << 4) + ln15, (s2 << 2) + quad);
        sacc[j] = __builtin_amdgcn_mfma_f32_16x16x32_f16(aq, bk, sacc[j], 0, 0, 0);
      }
    }

    float sv[4][4];
#pragma unroll
    for (int j = 0; j < 4; j++)
#pragma unroll
      for (int r = 0; r < 4; r++) sv[j][r] = sacc[j][r];

    if (!nomask) {
      int bi_k[4];
#pragma unroll
      for (int j = 0; j < 4; j++) {
        const int p = (kt << 6) + (j << 4) + ln15;
        bi_k[j] = (p / 96) * 6 + ((p % 24) >> 2);
      }
#pragma unroll
      for (int j = 0; j < 4; j++)
#pragma unroll
        for (int r = 0; r < 4; r++)
          if (bi_k[j] > bi_q[r]) sv[j][r] = -1e30f;
    }

    // online softmax; row r lives in the 16 lanes of this quad
#pragma unroll
    for (int r = 0; r < 4; r++) {
      float rm = fmaxf(fmaxf(sv[0][r], sv[1][r]), fmaxf(sv[2][r], sv[3][r]));
      rm = fmaxf(rm, __shfl_xor(rm, 1));
      rm = fmaxf(rm, __shfl_xor(rm, 2));
      rm = fmaxf(rm, __shfl_xor(rm, 4));
      rm = fmaxf(rm, __shfl_xor(rm, 8));
      const float mnew  = fmaxf(mrun[r], rm);
      const float alpha = __expf(mrun[r] - mnew);
      float rs = 0.f;
#pragma unroll
      for (int j = 0; j < 4; j++) {
        const float pj = __expf(sv[j][r] - mnew);
        sv[j][r] = pj; rs += pj;
      }
      rs += __shfl_xor(rs, 1);
      rs += __shfl_xor(rs, 2);
      rs += __shfl_xor(rs, 4);
      rs += __shfl_xor(rs, 8);
      lrun[r] = lrun[r] * alpha + rs;
      mrun[r] = mnew;
#pragma unroll
      for (int dt = 0; dt < 4; dt++) oacc[dt][r] *= alpha;
    }

    // P (f16) -> own rows of ps; wave-private, only a lgkm wait needed
#pragma unroll
    for (int j = 0; j < 4; j++)
#pragma unroll
      for (int r = 0; r < 4; r++) {
        const int row = (wave << 4) + (quad << 2) + r;
        const int col = (j << 4) + ln15;
        const int c = col >> 3, e = col & 7;
        ps[(((row << 3) + (c ^ (row & 7))) << 3) + e] = f16rn(sv[j][r]);
      }
    asm volatile("s_waitcnt lgkmcnt(0)" ::: "memory");

    // O += P V
#pragma unroll
    for (int s2 = 0; s2 < 2; ++s2) {
      const half8 pf = frag_read(ps, (wave << 4) + ln15, (s2 << 2) + quad);
#pragma unroll
      for (int dt = 0; dt < 4; dt++) {
        const half8 bv = frag_read(vhc, (dt << 4) + ln15, (s2 << 2) + quad);
        oacc[dt] = __builtin_amdgcn_mfma_f32_16x16x32_f16(pf, bv, oacc[dt], 0, 0, 0);
      }
    }

    __builtin_amdgcn_sched_barrier(0);
    __builtin_amdgcn_s_barrier();
    cur ^= 1;
  }

  // normalize + write f16 plane, token-major (M, C) for the proj GEMM
  const int b = bh / H_, h = bh % H_;
#pragma unroll
  for (int r = 0; r < 4; r++) {
    const float inv = 1.f / lrun[r];
    const int row_g = b * 576 + q0 + (wave << 4) + (quad << 2) + r;
#pragma unroll
    for (int dt = 0; dt < 4; dt++)
      Ap[(size_t)row_g * 768 + h * 64 + (dt << 4) + ln15] = f16rn(oacc[dt][r] * inv);
  }
}

// ---------------------------------------------------------------------------
extern "C" void kernel_launch(void* const* d_in, const int* in_sizes, int n_in,
                              void* d_out, int out_size, void* d_ws, size_t ws_size,
                              hipStream_t stream) {
  const float* x      = (const float*)d_in[0];
  const float* qkv_w  = (const float*)d_in[1];
  const float* qkv_b  = (const float*)d_in[2];
  const float* proj_w = (const float*)d_in[3];
  const float* proj_b = (const float*)d_in[4];
  float* out = (float*)d_out;

  // ws layout (all f16 planes, peak ~117 MB):
  // [Qp][Kp][Vt] planes 0-2; [Xp] plane 3 (x f16, dead after QKV -> overlaid
  // by attn-out Ap); [QWp] at 4nP (dead after QKV -> overlaid by PWp).
  ushort* ws = (ushort*)d_ws;
  const size_t nP = (size_t)M_ * C_;              // 14,155,776
  ushort* Qp  = ws + 0 * nP;
  ushort* Kp  = ws + 1 * nP;
  ushort* Vt  = ws + 2 * nP;
  ushort* Xp  = ws + 3 * nP;                      // x f16
  ushort* Ap  = ws + 3 * nP;                      // attn out (overlay Xp)
  ushort* QWp = ws + 4 * nP;                      // qkv_w f16
  ushort* PWp = ws + 4 * nP;                      // proj_w f16 (overlay QWp)

  // 1) convert x and qkv_w to f16
  cvt_f16<<<(M_*K_/4 + 255)/256, 256, 0, stream>>>(x, Xp, M_*K_/4);
  cvt_f16<<<(C3_*C_/4 + 255)/256, 256, 0, stream>>>(qkv_w, QWp, C3_*C_/4);

  // 2) qkv GEMM, epilogue scatters q/k/v planes
  gemm_mfma<0><<<dim3(C3_/256, M_/256), 512, 0, stream>>>(
      Xp, QWp, qkv_b, nullptr, Qp, Kp, Vt, C3_);

  // 3) attention (Xp now dead; writes Ap over it)
  attn_mfma<<<dim3(9, B_*H_), 256, 0, stream>>>(Qp, Kp, Vt, Ap);

  // 4) convert proj_w (QWp region dead after QKV GEMM)
  cvt_f16<<<(C_*C_/4 + 255)/256, 256, 0, stream>>>(proj_w, PWp, C_*C_/4);

  // 5) proj GEMM -> f32 out
  gemm_mfma<1><<<dim3(C_/256, M_/256), 512, 0, stream>>>(
      Ap, PWp, proj_b, out, nullptr, nullptr, nullptr, C_);
}

// Round 8
// 323.254 us; speedup vs baseline: 1.6425x; 1.0277x over previous
//
#include <hip/hip_runtime.h>
#include <stdint.h>

#define B_  32
#define N_  576
#define C_  768
#define H_  12
#define HD_ 64
#define M_  (B_*N_)    // 18432
#define C3_ (3*C_)     // 2304
#define K_  768

typedef __attribute__((ext_vector_type(8))) _Float16 half8;
typedef __attribute__((ext_vector_type(4))) float f32x4;

// f32 -> f16 round-to-nearest-even
__device__ __forceinline__ ushort f16rn(float x) {
  return __builtin_bit_cast(unsigned short, (_Float16)x);
}

// async global->LDS 16B DMA; LDS dest is wave-uniform base + lane*16
__device__ __forceinline__ void gload16(const ushort* g, ushort* l) {
  auto gp = (const __attribute__((address_space(1))) uint*)(g);
  auto lp = reinterpret_cast<__attribute__((address_space(3))) uint*>(
              reinterpret_cast<uintptr_t>(l));
  __builtin_amdgcn_global_load_lds(gp, lp, 16, 0, 0);
}

// swizzled 64-wide f16 tile: logical (row, chunk c of 8 halves) at slot
// row*8 + (c ^ (row&7)); DMA writes linear slots carrying the matching chunk.
__device__ __forceinline__ half8 frag_read(const ushort* t, int row, int c) {
  return *(const half8*)&t[((row << 3) + (c ^ (row & 7))) << 3];
}

// elementwise f32 -> f16 plane
__global__ __launch_bounds__(256)
void cvt_f16(const float* __restrict__ src, ushort* __restrict__ dst, int n4) {
  int i = blockIdx.x * 256 + threadIdx.x;
  if (i >= n4) return;
  float4 a = ((const float4*)src)[i];
  ((ushort4*)dst)[i] = make_ushort4(f16rn(a.x), f16rn(a.y), f16rn(a.z), f16rn(a.w));
}

// ---------------------------------------------------------------------------
// Plain f16 MFMA GEMM, 128x128 tile (retile from 256^2 -- the 2-barrier
// structure's best tile per m103 is 128^2=912 TF, and 4x the task count
// fixes the 648-wg packing quantization that capped r6 at 598 TF).
// 4 waves (2Mx2N, 64x64/wave), BK=32, double-buffered LDS 32KB -> 4
// blocks/CU (16 waves/CU), counted vmcnt(4) (never 0 mid-loop), raw
// s_barrier, setprio'd MFMA cluster, bijective XCD swizzle.
// Per wave per K-step: 8 ds_read_b128 + 16 MFMA (m97-faithful).
// EPI 0: scatter q (f16, pre-scaled 0.125) / k (f16) / v (f16, transposed)
// EPI 1: f32 output + bias (proj)
// ---------------------------------------------------------------------------
template<int EPI>
__global__ __launch_bounds__(256, 4)
void gemm_mfma(const ushort* __restrict__ A, const ushort* __restrict__ Bm,
               const float* __restrict__ bias, float* __restrict__ Cf,
               ushort* __restrict__ Qp, ushort* __restrict__ Kp,
               ushort* __restrict__ Vt, int Nout) {
  // [dbuf][plane: A,B][128 rows x 4 chunk-slots x 8 halves] = 32KB
  __shared__ ushort S[2][2][4096];

  const int tid  = threadIdx.x;
  const int lane = tid & 63, wave = tid >> 6;
  const int ln15 = lane & 15, cq = lane >> 4;
  const int wrow = (wave >> 1) << 6, wcol = (wave & 1) << 6;

  // XCD-aware bijective swizzle: both grids (2592, 864 wgs) are %8 == 0
  const int nbx  = gridDim.x;
  const int nwg  = nbx * gridDim.y;
  const int orig = blockIdx.y * nbx + blockIdx.x;
  const int swz  = (orig & 7) * (nwg >> 3) + (orig >> 3);
  const int m0 = (swz / nbx) << 7, n0 = (swz % nbx) << 7;

  int aslot[4], bslot[4];
#pragma unroll
  for (int i = 0; i < 4; i++) {
    const int r = wrow + (i << 4) + ln15;
    aslot[i] = (r << 2) + (cq ^ ((r >> 1) & 3));
  }
#pragma unroll
  for (int j = 0; j < 4; j++) {
    const int r = wcol + (j << 4) + ln15;
    bslot[j] = (r << 2) + (cq ^ ((r >> 1) & 3));
  }

  // staging: 2 parts x (A + B) = 4 gloads per thread per K-step
  int ldso[2];
  const ushort *pA[2], *pB[2];
#pragma unroll
  for (int p = 0; p < 2; p++) {
    const int s = (p << 8) + tid;            // linear 16B slot 0..511
    const int row = s >> 2, c = (s & 3) ^ ((row >> 1) & 3);
    ldso[p] = s << 3;
    pA[p] = A  + (size_t)(m0 + row) * K_ + (c << 3);
    pB[p] = Bm + (size_t)(n0 + row) * K_ + (c << 3);
  }

  auto issue4 = [&](int d, int k0) {
#pragma unroll
    for (int p = 0; p < 2; p++) {
      gload16(pA[p] + k0, &S[d][0][ldso[p]]);
      gload16(pB[p] + k0, &S[d][1][ldso[p]]);
    }
  };

  f32x4 acc[4][4];
#pragma unroll
  for (int i = 0; i < 4; i++)
#pragma unroll
    for (int j = 0; j < 4; j++) acc[i][j] = (f32x4)0.f;

  // prologue: tiles 0 and 1 in flight; wait tile 0 (my 4 newest stay out)
  issue4(0, 0);
  issue4(1, 32);
  asm volatile("s_waitcnt vmcnt(4)" ::: "memory");
  __builtin_amdgcn_s_barrier();
  __builtin_amdgcn_sched_barrier(0);

  constexpr int NT = K_ / 32;   // 24
  for (int t = 0; t < NT; ++t) {
    const int cur = t & 1;
    const ushort* As = &S[cur][0][0];
    const ushort* Bs = &S[cur][1][0];

    half8 bfr[4], afr[4];
#pragma unroll
    for (int j = 0; j < 4; j++) bfr[j] = *(const half8*)&Bs[bslot[j] << 3];
#pragma unroll
    for (int i = 0; i < 4; i++) afr[i] = *(const half8*)&As[aslot[i] << 3];

    __builtin_amdgcn_s_setprio(1);
#pragma unroll
    for (int j = 0; j < 4; ++j)
#pragma unroll
      for (int i = 0; i < 4; ++i)
        acc[i][j] = __builtin_amdgcn_mfma_f32_16x16x32_f16(afr[i], bfr[j], acc[i][j], 0, 0, 0);
    __builtin_amdgcn_s_setprio(0);

    if (t == NT - 1) break;
    // reads of S[cur] done -> barrier -> prefetch t+2 into S[cur] ->
    // wait tile t+1 landed (4 newest stay in flight) -> barrier
    asm volatile("s_waitcnt lgkmcnt(0)" ::: "memory");
    __builtin_amdgcn_sched_barrier(0);
    __builtin_amdgcn_s_barrier();
    if (t + 2 < NT) {
      issue4(cur, (t + 2) << 5);
      asm volatile("s_waitcnt vmcnt(4)" ::: "memory");
    } else {
      asm volatile("s_waitcnt vmcnt(0)" ::: "memory");
    }
    __builtin_amdgcn_s_barrier();
    __builtin_amdgcn_sched_barrier(0);
  }

  // epilogue: C/D layout col=lane&15, row=(lane>>4)*4+reg
  if (EPI == 1) {
#pragma unroll
    for (int j = 0; j < 4; j++) {
      const int col = n0 + wcol + (j << 4) + ln15;
      const float bv = bias[col];
#pragma unroll
      for (int i = 0; i < 4; i++)
#pragma unroll
        for (int r = 0; r < 4; r++) {
          const int row_g = m0 + wrow + (i << 4) + (cq << 2) + r;
          Cf[(size_t)row_g * Nout + col] = acc[i][j][r] + bv;
        }
    }
  } else {
#pragma unroll
    for (int j = 0; j < 4; j++) {
      const int col = n0 + wcol + (j << 4) + ln15;
      const int which = col / 768;              // block-uniform (128 | 768)
      const int hh = (col % 768) >> 6;
      const int dd = col & 63;
      const float bv = bias[col];
      const float scale = (which == 0) ? 0.125f : 1.f;
#pragma unroll
      for (int i = 0; i < 4; i++) {
        const int base_row = m0 + wrow + (i << 4) + (cq << 2);
        const int b = base_row / 576;           // constant across r (4 | 576)
        const int n = base_row - b * 576;
        const size_t bh = (size_t)b * H_ + hh;
        if (which == 2) {                       // V -> f16, (b,h,d,n)
          ushort hv[4];
#pragma unroll
          for (int r = 0; r < 4; r++) hv[r] = f16rn(acc[i][j][r] + bv);
          const size_t dst = (bh * 64 + dd) * 576 + n;
          *(ushort4*)&Vt[dst] = make_ushort4(hv[0], hv[1], hv[2], hv[3]);
        } else {                                // Q/K -> f16 plane (b,h,n,d)
          ushort* d = which ? Kp : Qp;
#pragma unroll
          for (int r = 0; r < 4; r++)
            d[(bh * 576 + n + r) * 64 + dd] = f16rn((acc[i][j][r] + bv) * scale);
        }
      }
    }
  }
}

// ---------------------------------------------------------------------------
// MFMA flash attention, block-causal, all-f16 single-product (8 MFMA QK^T +
// 8 MFMA PV per tile). K/V double-buffered with counted vmcnt(4) + raw
// s_barrier. LDS 48KB -> 3 blocks/CU. (unchanged from round 6)
// ---------------------------------------------------------------------------
__global__ __launch_bounds__(256, 3)
void attn_mfma(const ushort* __restrict__ Qp, const ushort* __restrict__ Kp,
               const ushort* __restrict__ Vp, ushort* __restrict__ Ap) {
  __shared__ ushort qs[4096], ks[2][4096], vs[2][4096], ps[4096];

  const int tid  = threadIdx.x;
  const int lane = tid & 63, wave = tid >> 6;
  const int ln15 = lane & 15, quad = lane >> 4;
  const int qt = blockIdx.x;                  // 0..8
  const int bh = blockIdx.y;                  // 0..383
  const int q0 = qt << 6;
  const size_t pbase = (size_t)bh * (576 * 64);

  // per-wave staging geometry: 2 parts x (16B per lane) covers 64x64 f16
  int sbs[2], srow[2], scol[2];
#pragma unroll
  for (int p = 0; p < 2; p++) {
    const int bs = ((wave << 1) + p) << 6;
    const int s = bs + lane, row = s >> 3, c = (s & 7) ^ (row & 7);
    sbs[p] = bs << 3; srow[p] = row; scol[p] = c << 3;
  }

  // stage Q (2 DMAs per wave)
#pragma unroll
  for (int p = 0; p < 2; p++)
    gload16(Qp + pbase + (size_t)(q0 + srow[p]) * 64 + scol[p], &qs[sbs[p]]);

  int bi_q[4];
#pragma unroll
  for (int r = 0; r < 4; r++) {
    const int p = q0 + (wave << 4) + (quad << 2) + r;
    bi_q[r] = (p / 96) * 6 + ((p % 24) >> 2);
  }
  const int qmax = 6 * ((qt * 64 + 159) / 96) - 1;
  const int qmin = 6 * ((2 * qt) / 3);

  // active K-tiles form a prefix (tmink nondecreasing in kt)
  int nkt = 0;
#pragma unroll
  for (int kt = 0; kt < 9; ++kt)
    if (6 * ((2 * kt) / 3) <= qmax) nkt = kt + 1;

  // prologue: stage K/V tile 0 into buf 0 (4 DMAs per wave)
#pragma unroll
  for (int p = 0; p < 2; p++) {
    gload16(Kp + pbase + (size_t)srow[p] * 64 + scol[p], &ks[0][sbs[p]]);
    gload16(Vp + pbase + (size_t)srow[p] * 576 + scol[p], &vs[0][sbs[p]]);
  }

  f32x4 oacc[4];
#pragma unroll
  for (int dt = 0; dt < 4; dt++) oacc[dt] = (f32x4)0.f;
  float mrun[4], lrun[4];
#pragma unroll
  for (int r = 0; r < 4; r++) { mrun[r] = -1e30f; lrun[r] = 0.f; }

  int cur = 0;
  for (int kt = 0; kt < nkt; ++kt) {
    const int tmaxk = 6 * ((kt * 64 + 159) / 96) - 1;
    const bool nomask = (tmaxk <= qmin);

    // prefetch tile kt+1 into the other buffer; wait tile kt with my 4
    // newest (kt+1) still in flight -> counted, never 0 mid-loop.
    if (kt + 1 < nkt) {
      const int nx = cur ^ 1;
#pragma unroll
      for (int p = 0; p < 2; p++) {
        gload16(Kp + pbase + (size_t)(((kt + 1) << 6) + srow[p]) * 64 + scol[p],
                &ks[nx][sbs[p]]);
        gload16(Vp + pbase + (size_t)srow[p] * 576 + ((kt + 1) << 6) + scol[p],
                &vs[nx][sbs[p]]);
      }
      asm volatile("s_waitcnt vmcnt(4)" ::: "memory");
    } else {
      asm volatile("s_waitcnt vmcnt(0)" ::: "memory");
    }
    __builtin_amdgcn_sched_barrier(0);
    __builtin_amdgcn_s_barrier();

    // S = Q K^T  (pre-scaled by 0.125 via Q)
    const ushort* khc = &ks[cur][0];
    const ushort* vhc = &vs[cur][0];
    f32x4 sacc[4];
#pragma unroll
    for (int j = 0; j < 4; j++) sacc[j] = (f32x4)0.f;
#pragma unroll
    for (int s2 = 0; s2 < 2; ++s2) {
      const half8 aq = frag_read(qs, (wave << 4) + ln15, (s2 << 2) + quad);
#pragma unroll
      for (int j = 0; j < 4; j++) {
        const half8 bk = frag_read(khc, (j << 4) + ln15, (s2 << 2) + quad);
        sacc[j] = __builtin_amdgcn_mfma_f32_16x16x32_f16(aq, bk, sacc[j], 0, 0, 0);
      }
    }

    float sv[4][4];
#pragma unroll
    for (int j = 0; j < 4; j++)
#pragma unroll
      for (int r = 0; r < 4; r++) sv[j][r] = sacc[j][r];

    if (!nomask) {
      int bi_k[4];
#pragma unroll
      for (int j = 0; j < 4; j++) {
        const int p = (kt << 6) + (j << 4) + ln15;
        bi_k[j] = (p / 96) * 6 + ((p % 24) >> 2);
      }
#pragma unroll
      for (int j = 0; j < 4; j++)
#pragma unroll
        for (int r = 0; r < 4; r++)
          if (bi_k[j] > bi_q[r]) sv[j][r] = -1e30f;
    }

    // online softmax; row r lives in the 16 lanes of this quad
#pragma unroll
    for (int r = 0; r < 4; r++) {
      float rm = fmaxf(fmaxf(sv[0][r], sv[1][r]), fmaxf(sv[2][r], sv[3][r]));
      rm = fmaxf(rm, __shfl_xor(rm, 1));
      rm = fmaxf(rm, __shfl_xor(rm, 2));
      rm = fmaxf(rm, __shfl_xor(rm, 4));
      rm = fmaxf(rm, __shfl_xor(rm, 8));
      const float mnew  = fmaxf(mrun[r], rm);
      const float alpha = __expf(mrun[r] - mnew);
      float rs = 0.f;
#pragma unroll
      for (int j = 0; j < 4; j++) {
        const float pj = __expf(sv[j][r] - mnew);
        sv[j][r] = pj; rs += pj;
      }
      rs += __shfl_xor(rs, 1);
      rs += __shfl_xor(rs, 2);
      rs += __shfl_xor(rs, 4);
      rs += __shfl_xor(rs, 8);
      lrun[r] = lrun[r] * alpha + rs;
      mrun[r] = mnew;
#pragma unroll
      for (int dt = 0; dt < 4; dt++) oacc[dt][r] *= alpha;
    }

    // P (f16) -> own rows of ps; wave-private, only a lgkm wait needed
#pragma unroll
    for (int j = 0; j < 4; j++)
#pragma unroll
      for (int r = 0; r < 4; r++) {
        const int row = (wave << 4) + (quad << 2) + r;
        const int col = (j << 4) + ln15;
        const int c = col >> 3, e = col & 7;
        ps[(((row << 3) + (c ^ (row & 7))) << 3) + e] = f16rn(sv[j][r]);
      }
    asm volatile("s_waitcnt lgkmcnt(0)" ::: "memory");

    // O += P V
#pragma unroll
    for (int s2 = 0; s2 < 2; ++s2) {
      const half8 pf = frag_read(ps, (wave << 4) + ln15, (s2 << 2) + quad);
#pragma unroll
      for (int dt = 0; dt < 4; dt++) {
        const half8 bv = frag_read(vhc, (dt << 4) + ln15, (s2 << 2) + quad);
        oacc[dt] = __builtin_amdgcn_mfma_f32_16x16x32_f16(pf, bv, oacc[dt], 0, 0, 0);
      }
    }

    __builtin_amdgcn_sched_barrier(0);
    __builtin_amdgcn_s_barrier();
    cur ^= 1;
  }

  // normalize + write f16 plane, token-major (M, C) for the proj GEMM
  const int b = bh / H_, h = bh % H_;
#pragma unroll
  for (int r = 0; r < 4; r++) {
    const float inv = 1.f / lrun[r];
    const int row_g = b * 576 + q0 + (wave << 4) + (quad << 2) + r;
#pragma unroll
    for (int dt = 0; dt < 4; dt++)
      Ap[(size_t)row_g * 768 + h * 64 + (dt << 4) + ln15] = f16rn(oacc[dt][r] * inv);
  }
}

// ---------------------------------------------------------------------------
extern "C" void kernel_launch(void* const* d_in, const int* in_sizes, int n_in,
                              void* d_out, int out_size, void* d_ws, size_t ws_size,
                              hipStream_t stream) {
  const float* x      = (const float*)d_in[0];
  const float* qkv_w  = (const float*)d_in[1];
  const float* qkv_b  = (const float*)d_in[2];
  const float* proj_w = (const float*)d_in[3];
  const float* proj_b = (const float*)d_in[4];
  float* out = (float*)d_out;

  // ws layout (all f16 planes, peak ~117 MB):
  // [Qp][Kp][Vt] planes 0-2; [Xp] plane 3 (x f16, dead after QKV -> overlaid
  // by attn-out Ap); [QWp] at 4nP (dead after QKV -> overlaid by PWp).
  ushort* ws = (ushort*)d_ws;
  const size_t nP = (size_t)M_ * C_;              // 14,155,776
  ushort* Qp  = ws + 0 * nP;
  ushort* Kp  = ws + 1 * nP;
  ushort* Vt  = ws + 2 * nP;
  ushort* Xp  = ws + 3 * nP;                      // x f16
  ushort* Ap  = ws + 3 * nP;                      // attn out (overlay Xp)
  ushort* QWp = ws + 4 * nP;                      // qkv_w f16
  ushort* PWp = ws + 4 * nP;                      // proj_w f16 (overlay QWp)

  // 1) convert x and qkv_w to f16
  cvt_f16<<<(M_*K_/4 + 255)/256, 256, 0, stream>>>(x, Xp, M_*K_/4);
  cvt_f16<<<(C3_*C_/4 + 255)/256, 256, 0, stream>>>(qkv_w, QWp, C3_*C_/4);

  // 2) qkv GEMM (128^2 tiles), epilogue scatters q/k/v planes
  gemm_mfma<0><<<dim3(C3_/128, M_/128), 256, 0, stream>>>(
      Xp, QWp, qkv_b, nullptr, Qp, Kp, Vt, C3_);

  // 3) attention (Xp now dead; writes Ap over it)
  attn_mfma<<<dim3(9, B_*H_), 256, 0, stream>>>(Qp, Kp, Vt, Ap);

  // 4) convert proj_w (QWp region dead after QKV GEMM)
  cvt_f16<<<(C_*C_/4 + 255)/256, 256, 0, stream>>>(proj_w, PWp, C_*C_/4);

  // 5) proj GEMM (128^2 tiles) -> f32 out
  gemm_mfma<1><<<dim3(C_/128, M_/128), 256, 0, stream>>>(
      Ap, PWp, proj_b, out, nullptr, nullptr, nullptr, C_);
}